// Round 7
// baseline (367.120 us; speedup 1.0000x reference)
//
#include <hip/hip_runtime.h>
#include <cstdint>

// Problem constants: B=2, S=2048, E=2048, H=16, D=128
#define S_LEN 2048
#define EMB   2048
#define NHEAD 16
#define HDIM  128
#define MROWS 4096   // B*S
#define NQKV  6144   // 3*E

typedef __bf16 bf16x8 __attribute__((ext_vector_type(8)));
typedef __bf16 bf16x4 __attribute__((ext_vector_type(4)));
typedef float  f32x4  __attribute__((ext_vector_type(4)));

#define MFMA16(a, b, c) __builtin_amdgcn_mfma_f32_16x16x32_bf16((a), (b), (c), 0, 0, 0)

__device__ __forceinline__ unsigned short f2bf(float f) {
  unsigned u = __builtin_bit_cast(unsigned, f);
  u += 0x7fffu + ((u >> 16) & 1u);   // RNE
  return (unsigned short)(u >> 16);
}
__device__ __forceinline__ float bf2f(unsigned short u) {
  unsigned v = ((unsigned)u) << 16;
  return __builtin_bit_cast(float, v);
}

// async global->LDS, 16B per lane. LDS dest must be wave-uniform base + lane*16.
__device__ __forceinline__ void gl_lds16(const unsigned short* g, unsigned short* l) {
  __builtin_amdgcn_global_load_lds(
      (const __attribute__((address_space(1))) void*)(uintptr_t)g,
      (__attribute__((address_space(3))) void*)(unsigned int)(uintptr_t)l,
      16, 0, 0);
}

#define FENCE() asm volatile("" ::: "memory")

// ---------------- cast fp32 -> bf16 (contiguous) ----------------
__global__ void cast_bf16(const float* __restrict__ in, unsigned short* __restrict__ out, int n) {
  int i = (blockIdx.x * 256 + threadIdx.x) * 4;
  if (i >= n) return;
  float4 v = *(const float4*)(in + i);
  ushort4 o;
  o.x = f2bf(v.x); o.y = f2bf(v.y); o.z = f2bf(v.z); o.w = f2bf(v.w);
  *(ushort4*)(out + i) = o;
}

// ---------------- transpose + cast: in[R][C] fp32 -> out[C][R] bf16 ----------------
__global__ void transpose_cast(const float* __restrict__ in, unsigned short* __restrict__ out,
                               int R, int C) {
  __shared__ float tile[32][33];
  int bx = blockIdx.x << 5;  // along C
  int by = blockIdx.y << 5;  // along R
  int tx = threadIdx.x, ty = threadIdx.y;
  for (int j = 0; j < 32; j += 8)
    tile[ty + j][tx] = in[(size_t)(by + ty + j) * C + bx + tx];
  __syncthreads();
  for (int j = 0; j < 32; j += 8)
    out[(size_t)(bx + ty + j) * R + by + tx] = f2bf(tile[tx][ty + j]);
}

// ---------------- GEMM1: C[M=4096][N=6144] = A[M][2048] @ Bt[N][2048]^T ----------------
// Round-0 verified kernel: BK=64, XOR-swizzled LDS, 128x128 tile, 3 blocks/CU TLP.
__global__ __launch_bounds__(256, 3) void gemm_qkv(const unsigned short* __restrict__ A,
                                                   const unsigned short* __restrict__ Bt,
                                                   unsigned short* __restrict__ Qo,
                                                   unsigned short* __restrict__ Ko,
                                                   unsigned short* __restrict__ Vt) {
  __shared__ __align__(16) unsigned short As[128 * 64];
  __shared__ __align__(16) unsigned short Bs[128 * 64];
  const int tid = threadIdx.x;
  const int n0 = blockIdx.x << 7;
  const int m0 = blockIdx.y << 7;
  const int wave = tid >> 6, lane = tid & 63;
  const int wm = (wave & 1) << 6, wn = (wave >> 1) << 6;
  const int fr = lane & 15, g = lane >> 4;
  const int q = tid >> 3;              // staging row (0..31 per issue)
  const int jp = tid & 7;              // staging granule within row
  f32x4 acc[4][4] = {};
  for (int k0 = 0; k0 < 2048; k0 += 64) {
    for (int i = 0; i < 4; ++i) {
      const int row = q + (i << 5);
      const int jsw = (jp ^ (row & 7)) << 3;
      gl_lds16(A + (size_t)(m0 + row) * 2048 + k0 + jsw, As + (row << 6) + (jp << 3));
      gl_lds16(Bt + (size_t)(n0 + row) * 2048 + k0 + jsw, Bs + (row << 6) + (jp << 3));
    }
    __builtin_amdgcn_s_waitcnt(0);
    __syncthreads();
    for (int ks = 0; ks < 2; ++ks) {
      const int slot = (((ks << 2) + g) ^ (fr & 7)) << 3;
      bf16x8 af[4], bfv[4];
      for (int i = 0; i < 4; ++i) af[i]  = *(const bf16x8*)(As + ((wm + (i << 4) + fr) << 6) + slot);
      for (int j = 0; j < 4; ++j) bfv[j] = *(const bf16x8*)(Bs + ((wn + (j << 4) + fr) << 6) + slot);
      for (int i = 0; i < 4; ++i)
        for (int j = 0; j < 4; ++j)
          acc[i][j] = MFMA16(af[i], bfv[j], acc[i][j]);
    }
    __syncthreads();
  }
  const int which = n0 >> 11;          // 0=Q 1=K 2=V
  const int h = (n0 >> 7) & 15;
  const int bb = m0 >> 11;
  const int bh = bb * NHEAD + h;
  for (int i = 0; i < 4; ++i) {
    const int sl = (m0 & (S_LEN - 1)) + wm + (i << 4) + (g << 2);
    for (int j = 0; j < 4; ++j) {
      const int d = wn + (j << 4) + fr;
      if (which == 2) {
        ushort4 pk;
        pk.x = f2bf(acc[i][j][0]); pk.y = f2bf(acc[i][j][1]);
        pk.z = f2bf(acc[i][j][2]); pk.w = f2bf(acc[i][j][3]);
        *(ushort4*)(Vt + ((size_t)bh * HDIM + d) * S_LEN + sl) = pk;
      } else {
        unsigned short* dst = (which == 0) ? Qo : Ko;
        for (int r = 0; r < 4; ++r)
          dst[((size_t)bh * S_LEN + sl + r) * HDIM + d] = f2bf(acc[i][j][r]);
      }
    }
  }
}

// ---------------- Flash attention, split-K + swizzled LDS, FIXED-MAX softmax ----------------
// Round-0 verified version: 768 blocks (3/CU), 48KB static LDS, syncthreads drains.
__global__ __launch_bounds__(256, 3) void attn(const unsigned short* __restrict__ Qg,
                                               const unsigned short* __restrict__ Kg,
                                               const unsigned short* __restrict__ Vtg,
                                               unsigned short* __restrict__ ctx,
                                               unsigned short* __restrict__ Opart,
                                               float* __restrict__ Lp) {
  __shared__ __align__(16) unsigned short SA[16384];  // 32KB: Qs alias Ks(16KB)+Vs(16KB)
  __shared__ __align__(16) unsigned short Ps[8192];   // 16KB C-layout-flat
  unsigned short* Qs = SA;
  unsigned short* Ks = SA;
  unsigned short* Vs = SA + 8192;

  const int blk = blockIdx.x;
  const int bh = blk & 31;
  const int t = blk >> 5;
  int qt, kt0, nkt, part;
  if (t < 8)       { qt = t;     kt0 = 0;  nkt = 2 * t + 2;       part = -1; }
  else if (t < 16) { qt = t;     kt0 = 0;  nkt = 16;              part = (bh << 3) + (qt - 8); }
  else             { qt = t - 8; kt0 = 16; nkt = 2 * qt - 14;     part = 256 + (bh << 3) + (qt - 8); }

  const int tid = threadIdx.x, wave = tid >> 6, lane = tid & 63;
  const int fr = lane & 15, g = lane >> 4;

  // stage Q tile [128][128], swizzled
  const unsigned short* qsrc = Qg + ((size_t)bh * S_LEN + (qt << 7)) * HDIM;
  for (int i = 0; i < 8; ++i) {
    int s0 = (i * 256 + tid) << 3;
    int q = s0 >> 7, jp = (s0 >> 3) & 15;
    gl_lds16(qsrc + (q << 7) + ((jp ^ (q & 15)) << 3), Qs + s0);
  }
  __builtin_amdgcn_s_waitcnt(0);
  __syncthreads();

  bf16x8 qf[2][4];
  for (int nbq = 0; nbq < 2; ++nbq)
    for (int kd = 0; kd < 4; ++kd) {
      int q = (wave << 5) + (nbq << 4) + fr;
      qf[nbq][kd] = *(const bf16x8*)(Qs + (q << 7) + ((((kd << 2) + g) ^ fr) << 3));
    }
  __syncthreads();  // Qs dead; SA becomes Ks/Vs

  float lsum[2] = {0.f, 0.f};  // per-lane partial of l (reduced in epilogue)
  f32x4 oacc[2][8] = {};
  const float scale = 0.08838834764831845f;  // 1/sqrt(128)

  const unsigned short* kbase = Kg + (size_t)bh * S_LEN * HDIM;
  const unsigned short* vbase = Vtg + (size_t)bh * HDIM * S_LEN;

  for (int kti = 0; kti < nkt; ++kti) {
    const int kt = kt0 + kti;
    // stage Ks[64][128] + Vs[128][64], swizzled
    const unsigned short* ks = kbase + ((size_t)kt << 6) * HDIM;
    const unsigned short* vs = vbase + (kt << 6);
    for (int i = 0; i < 4; ++i) {
      int s0 = (i * 256 + tid) << 3;
      int key = s0 >> 7, jk = (s0 >> 3) & 15;
      gl_lds16(ks + (key << 7) + ((jk ^ (key & 15)) << 3), Ks + s0);
      int d = s0 >> 6, jv = (s0 >> 3) & 7;
      gl_lds16(vs + (size_t)d * S_LEN + ((jv ^ (d & 7)) << 3), Vs + s0);
    }
    __builtin_amdgcn_s_waitcnt(0);
    __syncthreads();

    // S^T = K Q^T
    f32x4 sacc[2][4] = {};
    for (int kd = 0; kd < 4; ++kd)
      for (int kb = 0; kb < 4; ++kb) {
        bf16x8 kf = *(const bf16x8*)(Ks + (((kb << 4) + fr) << 7) + ((((kd << 2) + g) ^ fr) << 3));
        sacc[0][kb] = MFMA16(kf, qf[0][kd], sacc[0][kb]);
        sacc[1][kb] = MFMA16(kf, qf[1][kd], sacc[1][kb]);
      }

    // p = exp(s*scale), mask to 0 on diagonal tiles; accumulate per-lane l partials
    const bool diag = (kt >= 2 * qt);
    for (int nbq = 0; nbq < 2; ++nbq) {
      const int qg = (qt << 7) + (wave << 5) + (nbq << 4) + fr;
      float sum = 0.f;
      for (int kb = 0; kb < 4; ++kb) {
        float p[4];
        for (int r = 0; r < 4; ++r) {
          float v = sacc[nbq][kb][r] * scale;
          if (diag) {
            int keyg = (kt << 6) + (kb << 4) + (g << 2) + r;
            if (keyg > qg) v = -__builtin_inff();
          }
          p[r] = __expf(v);
          sum += p[r];
        }
        ushort4 pk;
        pk.x = f2bf(p[0]); pk.y = f2bf(p[1]);
        pk.z = f2bf(p[2]); pk.w = f2bf(p[3]);
        // C-layout-flat: [wave][nbq][kb][lane*4]
        *(ushort4*)(Ps + (((wave << 3) + (nbq << 2) + kb) << 8) + (lane << 2)) = pk;
      }
      lsum[nbq] += sum;
    }

    __builtin_amdgcn_s_waitcnt(0);  // drain Ps ds_writes before A-frag reads

    // O += P V
    for (int kc = 0; kc < 2; ++kc) {
      const int kbr = (kc << 1) + (g >> 1);
      bf16x8 ap[2];
      for (int h2 = 0; h2 < 2; ++h2) {
        const unsigned short* pb =
            Ps + (((wave << 3) + (h2 << 2) + kbr) << 8) + ((g & 1) << 7) + (fr << 2);
        bf16x4 a0 = *(const bf16x4*)pb;
        bf16x4 a1 = *(const bf16x4*)(pb + 64);
        bf16x8 a;
        a[0] = a0[0]; a[1] = a0[1]; a[2] = a0[2]; a[3] = a0[3];
        a[4] = a1[0]; a[5] = a1[1]; a[6] = a1[2]; a[7] = a1[3];
        ap[h2] = a;
      }
      for (int nd = 0; nd < 8; ++nd) {
        bf16x8 bv = *(const bf16x8*)(Vs + (((nd << 4) + fr) << 6) + ((((kc << 2) + g) ^ (fr & 7)) << 3));
        oacc[0][nd] = MFMA16(ap[0], bv, oacc[0][nd]);
        oacc[1][nd] = MFMA16(ap[1], bv, oacc[1][nd]);
      }
    }
    __syncthreads();  // all waves done with Ks/Vs before next stage
  }

  // reduce l partials across the 4 key-groups (once, not per-iter)
  for (int nbq = 0; nbq < 2; ++nbq) {
    lsum[nbq] += __shfl_xor(lsum[nbq], 16);
    lsum[nbq] += __shfl_xor(lsum[nbq], 32);
  }

  if (part < 0) {
    // full row: normalize + write ctx[b][s][h*128+d]
    const int b = bh >> 4, h = bh & 15;
    for (int mq = 0; mq < 2; ++mq)
      for (int r = 0; r < 4; ++r) {
        float lv = __shfl(lsum[mq], (lane & 48) | ((g << 2) + r));
        const float il = 1.0f / lv;
        const int s = (qt << 7) + (wave << 5) + (mq << 4) + (g << 2) + r;
        unsigned short* dst = ctx + ((size_t)(b * S_LEN + s) * EMB) + (h << 7);
        for (int nd = 0; nd < 8; ++nd)
          dst[(nd << 4) + fr] = f2bf(oacc[mq][nd][r] * il);
      }
  } else {
    // partial: unnormalized O' (bf16) + l (fp32)
    unsigned short* Ob = Opart + ((size_t)part << 14);
    for (int mq = 0; mq < 2; ++mq)
      for (int r = 0; r < 4; ++r) {
        const int ql = (wave << 5) + (mq << 4) + (g << 2) + r;
        unsigned short* dst = Ob + (ql << 7);
        for (int nd = 0; nd < 8; ++nd)
          dst[(nd << 4) + fr] = f2bf(oacc[mq][nd][r]);
      }
    if (g == 0)
      for (int nbq = 0; nbq < 2; ++nbq) {
        const int ql = (wave << 5) + (nbq << 4) + fr;
        Lp[(part << 7) + ql] = lsum[nbq];
      }
  }
}

// ---------------- combine partials for qt in [8,16) ----------------
__global__ void attn_combine(const unsigned short* __restrict__ Op,
                             const float* __restrict__ Lp,
                             unsigned short* __restrict__ ctx) {
  const int tid = threadIdx.x;
  const int rid = blockIdx.x * 16 + (tid >> 4);  // 0..32767
  const int l16 = tid & 15;
  const int bh = rid >> 10;
  const int qtl = (rid >> 7) & 7;
  const int ql = rid & 127;
  const int p = (bh << 3) + qtl;
  const float lA = Lp[(p << 7) + ql];
  const float lB = Lp[((256 + p) << 7) + ql];
  const float il = 1.0f / (lA + lB);
  const int d0 = l16 << 3;
  const unsigned short* a = Op + ((size_t)p << 14) + (ql << 7) + d0;
  const unsigned short* b = Op + ((size_t)(256 + p) << 14) + (ql << 7) + d0;
  const int bb = bh >> 4, h = bh & 15;
  const int s = ((qtl + 8) << 7) + ql;
  unsigned short* dst = ctx + ((size_t)(bb * S_LEN + s) * EMB) + (h << 7) + d0;
  ushort4 va0 = *(const ushort4*)a, va1 = *(const ushort4*)(a + 4);
  ushort4 vb0 = *(const ushort4*)b, vb1 = *(const ushort4*)(b + 4);
  ushort4 o0, o1;
  o0.x = f2bf((bf2f(va0.x) + bf2f(vb0.x)) * il);
  o0.y = f2bf((bf2f(va0.y) + bf2f(vb0.y)) * il);
  o0.z = f2bf((bf2f(va0.z) + bf2f(vb0.z)) * il);
  o0.w = f2bf((bf2f(va0.w) + bf2f(vb0.w)) * il);
  o1.x = f2bf((bf2f(va1.x) + bf2f(vb1.x)) * il);
  o1.y = f2bf((bf2f(va1.y) + bf2f(vb1.y)) * il);
  o1.z = f2bf((bf2f(va1.z) + bf2f(vb1.z)) * il);
  o1.w = f2bf((bf2f(va1.w) + bf2f(vb1.w)) * il);
  *(ushort4*)dst = o0;
  *(ushort4*)(dst + 4) = o1;
}

// ---------------- GEMM2 (r1-measured fast variant): 256x128 tile, 8 waves, pipelined ----------------
__device__ __forceinline__ void gemm_pipe(const unsigned short* __restrict__ Ap,
                                          const unsigned short* __restrict__ Bp,
                                          int m0, int n0, f32x4 (&acc)[4][4]) {
  extern __shared__ unsigned short glds[];
  unsigned short* As = glds;          // [2][256*64]
  unsigned short* Bs = glds + 32768;  // [2][128*64]
  const int tid = threadIdx.x;
  const int w = tid >> 6, lane = tid & 63;
  const int fr = lane & 15, g = lane >> 4;
  const int wm = (w >> 1) << 6;      // 0,64,128,192
  const int wn = (w & 1) << 6;       // 0,64
  const int q = tid >> 3, jp = tid & 7;

  auto stageA = [&](int buf, int kk) {
#pragma unroll
    for (int i = 0; i < 4; ++i) {
      const int row = q + (i << 6);
      gl_lds16(Ap + (size_t)(m0 + row) * 2048 + kk + ((jp ^ (row & 7)) << 3),
               As + buf * 16384 + (row << 6) + (jp << 3));
    }
  };
  auto stageB = [&](int buf, int kk) {
#pragma unroll
    for (int i = 0; i < 2; ++i) {
      const int row = q + (i << 6);
      gl_lds16(Bp + (size_t)(n0 + row) * 2048 + kk + ((jp ^ (row & 7)) << 3),
               Bs + buf * 8192 + (row << 6) + (jp << 3));
    }
  };

  stageA(0, 0); stageB(0, 0);
  int cur = 0;
#pragma unroll 2
  for (int t = 0; t < 32; ++t) {
    if (t < 31) {
      const int kn = (t + 1) << 6;
      stageA(cur ^ 1, kn); stageB(cur ^ 1, kn);
      asm volatile("s_waitcnt vmcnt(6)" ::: "memory");
    } else {
      asm volatile("s_waitcnt vmcnt(0)" ::: "memory");
    }
    __builtin_amdgcn_s_barrier();
    FENCE();

    const unsigned short* Ab = As + cur * 16384;
    const unsigned short* Bb = Bs + cur * 8192;

    bf16x8 af[4][2], bv[2][2];
#pragma unroll
    for (int i = 0; i < 4; ++i)
#pragma unroll
      for (int ks = 0; ks < 2; ++ks)
        af[i][ks] = *(const bf16x8*)(Ab + ((wm + (i << 4) + fr) << 6) +
                                     ((((ks << 2) + g) ^ (fr & 7)) << 3));
#pragma unroll
    for (int j = 0; j < 2; ++j)
#pragma unroll
      for (int ks = 0; ks < 2; ++ks)
        bv[j][ks] = *(const bf16x8*)(Bb + ((wn + (j << 4) + fr) << 6) +
                                     ((((ks << 2) + g) ^ (fr & 7)) << 3));
    __builtin_amdgcn_s_setprio(1);
#pragma unroll
    for (int ks = 0; ks < 2; ++ks)
#pragma unroll
      for (int i = 0; i < 4; ++i)
#pragma unroll
        for (int j = 0; j < 2; ++j)
          acc[i][j] = MFMA16(af[i][ks], bv[j][ks], acc[i][j]);
    __builtin_amdgcn_s_setprio(0);
    FENCE();
    __builtin_amdgcn_s_barrier();

    bf16x8 bw[2][2];
#pragma unroll
    for (int j = 0; j < 2; ++j)
#pragma unroll
      for (int ks = 0; ks < 2; ++ks)
        bw[j][ks] = *(const bf16x8*)(Bb + ((wn + ((j + 2) << 4) + fr) << 6) +
                                     ((((ks << 2) + g) ^ (fr & 7)) << 3));
    __builtin_amdgcn_s_setprio(1);
#pragma unroll
    for (int ks = 0; ks < 2; ++ks)
#pragma unroll
      for (int i = 0; i < 4; ++i)
#pragma unroll
        for (int j = 0; j < 2; ++j)
          acc[i][j + 2] = MFMA16(af[i][ks], bw[j][ks], acc[i][j + 2]);
    __builtin_amdgcn_s_setprio(0);
    FENCE();
    __builtin_amdgcn_s_barrier();
    cur ^= 1;
  }
}

// grid 256 (16 m-tiles x 16 n-tiles) -> exactly 1 block/CU, 1 round.
__global__ __launch_bounds__(512, 2) void gemm8_out(const unsigned short* __restrict__ A,
                                                    const unsigned short* __restrict__ Bt,
                                                    float* __restrict__ C) {
  const int bid = blockIdx.x;
  const int wg = (bid & 7) * 32 + (bid >> 3);
  const int mt = wg >> 4, nt = wg & 15;
  const int m0 = mt << 8, n0 = nt << 7;
  f32x4 acc[4][4] = {};
  gemm_pipe(A, Bt, m0, n0, acc);

  const int tid = threadIdx.x, w = tid >> 6, lane = tid & 63;
  const int fr = lane & 15, g = lane >> 4;
  const int wm = (w >> 1) << 6, wn = (w & 1) << 6;
  for (int i = 0; i < 4; ++i) {
    const int row = m0 + wm + (i << 4) + (g << 2);
    for (int j = 0; j < 4; ++j) {
      const int col = n0 + wn + (j << 4) + fr;
      for (int r = 0; r < 4; ++r)
        C[(size_t)(row + r) * EMB + col] = acc[i][j][r];
    }
  }
}

extern "C" void kernel_launch(void* const* d_in, const int* in_sizes, int n_in,
                              void* d_out, int out_size, void* d_ws, size_t ws_size,
                              hipStream_t stream) {
  const float* x    = (const float*)d_in[0];
  const float* wqkv = (const float*)d_in[1];
  const float* wout = (const float*)d_in[2];
  float* out = (float*)d_out;

  unsigned short* ws = (unsigned short*)d_ws;
  const size_t NELEM = (size_t)MROWS * EMB;            // 8388608
  unsigned short* xb    = ws;                          // reused as ctx
  unsigned short* wqkvT = xb + NELEM;                  // [6144][2048]; dead after gemm_qkv
  unsigned short* woutT = wqkvT + (size_t)NQKV * EMB;  // [2048][2048]
  unsigned short* Q     = woutT + (size_t)EMB * EMB;   // [32][2048][128]
  unsigned short* K     = Q + NELEM;
  unsigned short* Vt    = K + NELEM;                   // [32][128][2048]
  unsigned short* ctx   = xb;                          // alias: xb dead after gemm_qkv
  unsigned short* Opart = wqkvT;                       // alias: 512*16384 = 8.39M shorts
  float* Lp = (float*)(Opart + ((size_t)512 << 14));   // in wqkvT spare (12.58M region)

  static bool attr_done = false;
  if (!attr_done) {
    (void)hipFuncSetAttribute((const void*)gemm8_out,
                              hipFuncAttributeMaxDynamicSharedMemorySize, 98304);
    attr_done = true;
  }

  cast_bf16<<<8192, 256, 0, stream>>>(x, xb, (int)NELEM);
  transpose_cast<<<dim3(NQKV / 32, EMB / 32), dim3(32, 8), 0, stream>>>(wqkv, wqkvT, EMB, NQKV);
  transpose_cast<<<dim3(EMB / 32, EMB / 32), dim3(32, 8), 0, stream>>>(wout, woutT, EMB, EMB);
  gemm_qkv<<<dim3(NQKV / 128, MROWS / 128), 256, 0, stream>>>(xb, wqkvT, Q, K, Vt);
  attn<<<768, 256, 0, stream>>>(Q, K, Vt, ctx, Opart, Lp);
  attn_combine<<<2048, 256, 0, stream>>>(Opart, Lp, ctx);
  gemm8_out<<<256, 512, 98304, stream>>>(ctx, woutT, out);
}

// Round 8
// 355.395 us; speedup vs baseline: 1.0330x; 1.0330x over previous
//
#include <hip/hip_runtime.h>
#include <cstdint>

// Problem constants: B=2, S=2048, E=2048, H=16, D=128
#define S_LEN 2048
#define EMB   2048
#define NHEAD 16
#define HDIM  128
#define MROWS 4096   // B*S
#define NQKV  6144   // 3*E

typedef __bf16 bf16x8 __attribute__((ext_vector_type(8)));
typedef __bf16 bf16x4 __attribute__((ext_vector_type(4)));
typedef float  f32x4  __attribute__((ext_vector_type(4)));

#define MFMA16(a, b, c) __builtin_amdgcn_mfma_f32_16x16x32_bf16((a), (b), (c), 0, 0, 0)

__device__ __forceinline__ unsigned short f2bf(float f) {
  unsigned u = __builtin_bit_cast(unsigned, f);
  u += 0x7fffu + ((u >> 16) & 1u);   // RNE
  return (unsigned short)(u >> 16);
}
__device__ __forceinline__ float bf2f(unsigned short u) {
  unsigned v = ((unsigned)u) << 16;
  return __builtin_bit_cast(float, v);
}

// async global->LDS, 16B per lane. LDS dest must be wave-uniform base + lane*16.
__device__ __forceinline__ void gl_lds16(const unsigned short* g, unsigned short* l) {
  __builtin_amdgcn_global_load_lds(
      (const __attribute__((address_space(1))) void*)(uintptr_t)g,
      (__attribute__((address_space(3))) void*)(unsigned int)(uintptr_t)l,
      16, 0, 0);
}

#define FENCE() asm volatile("" ::: "memory")

// ---------------- fused preprocessing: cast x + transpose wqkv + transpose wout ----------------
// grid = 8192 (cast) + 6144 (wqkv T) + 2048 (wout T). One launch instead of three.
// Transpose: 64(in-rows) x 32(in-cols) tile; reads 128B/row coalesced; writes ushort4
// (128B per out-row, 8B/lane); LDS [64][33] fp32 pad -> 2-way conflicts only (free).
__global__ __launch_bounds__(256) void prep(const float* __restrict__ x,
                                            const float* __restrict__ wqkv,
                                            const float* __restrict__ wout,
                                            unsigned short* __restrict__ xb,
                                            unsigned short* __restrict__ wqkvT,
                                            unsigned short* __restrict__ woutT) {
  const int bid = blockIdx.x;
  if (bid < 8192) {                      // ---- cast x: fp32 -> bf16, 4 elems/thread ----
    int i = (bid * 256 + threadIdx.x) * 4;
    float4 v = *(const float4*)(x + i);
    ushort4 o;
    o.x = f2bf(v.x); o.y = f2bf(v.y); o.z = f2bf(v.z); o.w = f2bf(v.w);
    *(ushort4*)(xb + i) = o;
    return;
  }
  // ---- transpose+cast: in[R][C] fp32 -> out[C][R] bf16 ----
  const float* in; unsigned short* out; int C, tb;
  if (bid < 8192 + 6144) { in = wqkv; out = wqkvT; C = NQKV; tb = bid - 8192; }
  else                   { in = wout; out = woutT; C = EMB;  tb = bid - 8192 - 6144; }
  const int R = EMB;                     // both inputs have 2048 rows
  const int ctiles = C >> 5;
  const int by = (tb / ctiles) << 6;     // in-row block (64)
  const int bx = (tb % ctiles) << 5;     // in-col block (32)
  __shared__ float tile[64][33];
  const int tx = threadIdx.x & 31, ty = threadIdx.x >> 5;   // ty 0..7
  for (int j = 0; j < 64; j += 8)
    tile[ty + j][tx] = in[(size_t)(by + ty + j) * C + bx + tx];
  __syncthreads();
  int c = threadIdx.x >> 4;              // 0..15, +16 second pass
  const int r4 = (threadIdx.x & 15) << 2;
  for (int p = 0; p < 2; ++p, c += 16) {
    ushort4 o;
    o.x = f2bf(tile[r4 + 0][c]);
    o.y = f2bf(tile[r4 + 1][c]);
    o.z = f2bf(tile[r4 + 2][c]);
    o.w = f2bf(tile[r4 + 3][c]);
    *(ushort4*)(out + (size_t)(bx + c) * R + by + r4) = o;
  }
}

// ---------------- GEMM1: C[M=4096][N=6144] = A[M][2048] @ Bt[N][2048]^T ----------------
// Round-0 verified kernel: BK=64, XOR-swizzled LDS, 128x128 tile, 3 blocks/CU TLP.
__global__ __launch_bounds__(256, 3) void gemm_qkv(const unsigned short* __restrict__ A,
                                                   const unsigned short* __restrict__ Bt,
                                                   unsigned short* __restrict__ Qo,
                                                   unsigned short* __restrict__ Ko,
                                                   unsigned short* __restrict__ Vt) {
  __shared__ __align__(16) unsigned short As[128 * 64];
  __shared__ __align__(16) unsigned short Bs[128 * 64];
  const int tid = threadIdx.x;
  const int n0 = blockIdx.x << 7;
  const int m0 = blockIdx.y << 7;
  const int wave = tid >> 6, lane = tid & 63;
  const int wm = (wave & 1) << 6, wn = (wave >> 1) << 6;
  const int fr = lane & 15, g = lane >> 4;
  const int q = tid >> 3;              // staging row (0..31 per issue)
  const int jp = tid & 7;              // staging granule within row
  f32x4 acc[4][4] = {};
  for (int k0 = 0; k0 < 2048; k0 += 64) {
    for (int i = 0; i < 4; ++i) {
      const int row = q + (i << 5);
      const int jsw = (jp ^ (row & 7)) << 3;
      gl_lds16(A + (size_t)(m0 + row) * 2048 + k0 + jsw, As + (row << 6) + (jp << 3));
      gl_lds16(Bt + (size_t)(n0 + row) * 2048 + k0 + jsw, Bs + (row << 6) + (jp << 3));
    }
    __builtin_amdgcn_s_waitcnt(0);
    __syncthreads();
    for (int ks = 0; ks < 2; ++ks) {
      const int slot = (((ks << 2) + g) ^ (fr & 7)) << 3;
      bf16x8 af[4], bfv[4];
      for (int i = 0; i < 4; ++i) af[i]  = *(const bf16x8*)(As + ((wm + (i << 4) + fr) << 6) + slot);
      for (int j = 0; j < 4; ++j) bfv[j] = *(const bf16x8*)(Bs + ((wn + (j << 4) + fr) << 6) + slot);
      for (int i = 0; i < 4; ++i)
        for (int j = 0; j < 4; ++j)
          acc[i][j] = MFMA16(af[i], bfv[j], acc[i][j]);
    }
    __syncthreads();
  }
  const int which = n0 >> 11;          // 0=Q 1=K 2=V
  const int h = (n0 >> 7) & 15;
  const int bb = m0 >> 11;
  const int bh = bb * NHEAD + h;
  for (int i = 0; i < 4; ++i) {
    const int sl = (m0 & (S_LEN - 1)) + wm + (i << 4) + (g << 2);
    for (int j = 0; j < 4; ++j) {
      const int d = wn + (j << 4) + fr;
      if (which == 2) {
        ushort4 pk;
        pk.x = f2bf(acc[i][j][0]); pk.y = f2bf(acc[i][j][1]);
        pk.z = f2bf(acc[i][j][2]); pk.w = f2bf(acc[i][j][3]);
        *(ushort4*)(Vt + ((size_t)bh * HDIM + d) * S_LEN + sl) = pk;
      } else {
        unsigned short* dst = (which == 0) ? Qo : Ko;
        for (int r = 0; r < 4; ++r)
          dst[((size_t)bh * S_LEN + sl + r) * HDIM + d] = f2bf(acc[i][j][r]);
      }
    }
  }
}

// ---------------- Flash attention, DOUBLE-BUFFERED K/V staging (r6 best variant) ----------------
// 768 blocks, 2/CU (80KB dynamic LDS). bh=blk&31. K/V dbuf + counted vmcnt(8) + raw
// s_barriers; tile t+1's 8 gl_lds issue right after the end-of-tile barrier; only tile
// t's loads are forced per iteration. Ps drain is lgkmcnt-only.
__global__ __launch_bounds__(256, 2) void attn(const unsigned short* __restrict__ Qg,
                                               const unsigned short* __restrict__ Kg,
                                               const unsigned short* __restrict__ Vtg,
                                               unsigned short* __restrict__ ctx,
                                               unsigned short* __restrict__ Opart,
                                               float* __restrict__ Lp) {
  extern __shared__ __align__(16) unsigned short lds[];
  unsigned short* KV = lds;            // K: [2][8192] @0, V: [2][8192] @16384 (shorts)
  unsigned short* Ps = lds + 32768;    // 16KB C-layout-flat
  unsigned short* Qs = lds;            // alias over K0|K1 (dead after qf read)

  const int blk = blockIdx.x;
  const int bh = blk & 31;
  const int t = blk >> 5;
  int qt, kt0, nkt, part;
  if (t < 8)       { qt = t;     kt0 = 0;  nkt = 2 * t + 2;       part = -1; }
  else if (t < 16) { qt = t;     kt0 = 0;  nkt = 16;              part = (bh << 3) + (qt - 8); }
  else             { qt = t - 8; kt0 = 16; nkt = 2 * qt - 14;     part = 256 + (bh << 3) + (qt - 8); }

  const int tid = threadIdx.x, wave = tid >> 6, lane = tid & 63;
  const int fr = lane & 15, g = lane >> 4;

  // stage Q tile [128][128], swizzled
  const unsigned short* qsrc = Qg + ((size_t)bh * S_LEN + (qt << 7)) * HDIM;
  for (int i = 0; i < 8; ++i) {
    int s0 = (i * 256 + tid) << 3;
    int q = s0 >> 7, jp = (s0 >> 3) & 15;
    gl_lds16(qsrc + (q << 7) + ((jp ^ (q & 15)) << 3), Qs + s0);
  }
  __builtin_amdgcn_s_waitcnt(0);
  __syncthreads();

  bf16x8 qf[2][4];
  for (int nbq = 0; nbq < 2; ++nbq)
    for (int kd = 0; kd < 4; ++kd) {
      int q = (wave << 5) + (nbq << 4) + fr;
      qf[nbq][kd] = *(const bf16x8*)(Qs + (q << 7) + ((((kd << 2) + g) ^ fr) << 3));
    }
  __syncthreads();  // Qs dead; region becomes K dbuf

  float lsum[2] = {0.f, 0.f};
  f32x4 oacc[2][8] = {};
  const float scale = 0.08838834764831845f;  // 1/sqrt(128)

  const unsigned short* kbase = Kg + (size_t)bh * S_LEN * HDIM;
  const unsigned short* vbase = Vtg + (size_t)bh * HDIM * S_LEN;

  // stage K[64][128] + V[128][64] for tile kt into buffer cur (8 gl_lds per wave)
  auto stageKV = [&](int cur, int kt) {
    const unsigned short* ks = kbase + ((size_t)kt << 6) * HDIM;
    const unsigned short* vs = vbase + (kt << 6);
    unsigned short* Kd = KV + (cur << 13);
    unsigned short* Vd = KV + 16384 + (cur << 13);
#pragma unroll
    for (int i = 0; i < 4; ++i) {
      int s0 = (i * 256 + tid) << 3;
      int key = s0 >> 7, jk = (s0 >> 3) & 15;
      gl_lds16(ks + (key << 7) + ((jk ^ (key & 15)) << 3), Kd + s0);
      int d = s0 >> 6, jv = (s0 >> 3) & 7;
      gl_lds16(vs + (size_t)d * S_LEN + ((jv ^ (d & 7)) << 3), Vd + s0);
    }
  };

  stageKV(0, kt0);   // prologue: tile 0 in flight (8 outstanding/wave)

  for (int kti = 0; kti < nkt; ++kti) {
    const int cur = kti & 1;
    const int kt = kt0 + kti;
    if (kti + 1 < nkt) {
      stageKV(cur ^ 1, kt + 1);                         // issue early (16 outstanding)
      asm volatile("s_waitcnt vmcnt(8)" ::: "memory");  // force tile kti only
    } else {
      asm volatile("s_waitcnt vmcnt(0)" ::: "memory");
    }
    FENCE(); __builtin_amdgcn_s_barrier(); FENCE();     // buf[cur] ready on all waves

    const unsigned short* Kc = KV + (cur << 13);
    const unsigned short* Vc = KV + 16384 + (cur << 13);

    // S^T = K Q^T
    f32x4 sacc[2][4] = {};
    for (int kd = 0; kd < 4; ++kd)
      for (int kb = 0; kb < 4; ++kb) {
        bf16x8 kf = *(const bf16x8*)(Kc + (((kb << 4) + fr) << 7) + ((((kd << 2) + g) ^ fr) << 3));
        sacc[0][kb] = MFMA16(kf, qf[0][kd], sacc[0][kb]);
        sacc[1][kb] = MFMA16(kf, qf[1][kd], sacc[1][kb]);
      }

    // p = exp(s*scale), mask on diagonal tiles; per-lane l partials
    const bool diag = (kt >= 2 * qt);
    for (int nbq = 0; nbq < 2; ++nbq) {
      const int qg = (qt << 7) + (wave << 5) + (nbq << 4) + fr;
      float sum = 0.f;
      for (int kb = 0; kb < 4; ++kb) {
        float p[4];
        for (int r = 0; r < 4; ++r) {
          float v = sacc[nbq][kb][r] * scale;
          if (diag) {
            int keyg = (kt << 6) + (kb << 4) + (g << 2) + r;
            if (keyg > qg) v = -__builtin_inff();
          }
          p[r] = __expf(v);
          sum += p[r];
        }
        ushort4 pk;
        pk.x = f2bf(p[0]); pk.y = f2bf(p[1]);
        pk.z = f2bf(p[2]); pk.w = f2bf(p[3]);
        *(ushort4*)(Ps + (((wave << 3) + (nbq << 2) + kb) << 8) + (lane << 2)) = pk;
      }
      lsum[nbq] += sum;
    }

    // drain Ps ds_writes ONLY (lgkm), keep prefetch DMA (vmcnt) in flight
    asm volatile("s_waitcnt lgkmcnt(0)" ::: "memory");
    __builtin_amdgcn_sched_barrier(0);

    // O += P V (each wave reads only its own Ps region)
    for (int kc = 0; kc < 2; ++kc) {
      const int kbr = (kc << 1) + (g >> 1);
      bf16x8 ap[2];
      for (int h2 = 0; h2 < 2; ++h2) {
        const unsigned short* pb =
            Ps + (((wave << 3) + (h2 << 2) + kbr) << 8) + ((g & 1) << 7) + (fr << 2);
        bf16x4 a0 = *(const bf16x4*)pb;
        bf16x4 a1 = *(const bf16x4*)(pb + 64);
        bf16x8 a;
        a[0] = a0[0]; a[1] = a0[1]; a[2] = a0[2]; a[3] = a0[3];
        a[4] = a1[0]; a[5] = a1[1]; a[6] = a1[2]; a[7] = a1[3];
        ap[h2] = a;
      }
      for (int nd = 0; nd < 8; ++nd) {
        bf16x8 bv = *(const bf16x8*)(Vc + (((nd << 4) + fr) << 6) + ((((kc << 2) + g) ^ (fr & 7)) << 3));
        oacc[0][nd] = MFMA16(ap[0], bv, oacc[0][nd]);
        oacc[1][nd] = MFMA16(ap[1], bv, oacc[1][nd]);
      }
    }
    FENCE(); __builtin_amdgcn_s_barrier(); FENCE();   // all waves done with buf[cur]
  }

  // reduce l partials across the 4 key-groups (once, not per-iter)
  for (int nbq = 0; nbq < 2; ++nbq) {
    lsum[nbq] += __shfl_xor(lsum[nbq], 16);
    lsum[nbq] += __shfl_xor(lsum[nbq], 32);
  }

  if (part < 0) {
    const int b = bh >> 4, h = bh & 15;
    for (int mq = 0; mq < 2; ++mq)
      for (int r = 0; r < 4; ++r) {
        float lv = __shfl(lsum[mq], (lane & 48) | ((g << 2) + r));
        const float il = 1.0f / lv;
        const int s = (qt << 7) + (wave << 5) + (mq << 4) + (g << 2) + r;
        unsigned short* dst = ctx + ((size_t)(b * S_LEN + s) * EMB) + (h << 7);
        for (int nd = 0; nd < 8; ++nd)
          dst[(nd << 4) + fr] = f2bf(oacc[mq][nd][r] * il);
      }
  } else {
    unsigned short* Ob = Opart + ((size_t)part << 14);
    for (int mq = 0; mq < 2; ++mq)
      for (int r = 0; r < 4; ++r) {
        const int ql = (wave << 5) + (mq << 4) + (g << 2) + r;
        unsigned short* dst = Ob + (ql << 7);
        for (int nd = 0; nd < 8; ++nd)
          dst[(nd << 4) + fr] = f2bf(oacc[mq][nd][r]);
      }
    if (g == 0)
      for (int nbq = 0; nbq < 2; ++nbq) {
        const int ql = (wave << 5) + (nbq << 4) + fr;
        Lp[(part << 7) + ql] = lsum[nbq];
      }
  }
}

// ---------------- combine partials for qt in [8,16) ----------------
__global__ void attn_combine(const unsigned short* __restrict__ Op,
                             const float* __restrict__ Lp,
                             unsigned short* __restrict__ ctx) {
  const int tid = threadIdx.x;
  const int rid = blockIdx.x * 16 + (tid >> 4);  // 0..32767
  const int l16 = tid & 15;
  const int bh = rid >> 10;
  const int qtl = (rid >> 7) & 7;
  const int ql = rid & 127;
  const int p = (bh << 3) + qtl;
  const float lA = Lp[(p << 7) + ql];
  const float lB = Lp[((256 + p) << 7) + ql];
  const float il = 1.0f / (lA + lB);
  const int d0 = l16 << 3;
  const unsigned short* a = Op + ((size_t)p << 14) + (ql << 7) + d0;
  const unsigned short* b = Op + ((size_t)(256 + p) << 14) + (ql << 7) + d0;
  const int bb = bh >> 4, h = bh & 15;
  const int s = ((qtl + 8) << 7) + ql;
  unsigned short* dst = ctx + ((size_t)(bb * S_LEN + s) * EMB) + (h << 7) + d0;
  ushort4 va0 = *(const ushort4*)a, va1 = *(const ushort4*)(a + 4);
  ushort4 vb0 = *(const ushort4*)b, vb1 = *(const ushort4*)(b + 4);
  ushort4 o0, o1;
  o0.x = f2bf((bf2f(va0.x) + bf2f(vb0.x)) * il);
  o0.y = f2bf((bf2f(va0.y) + bf2f(vb0.y)) * il);
  o0.z = f2bf((bf2f(va0.z) + bf2f(vb0.z)) * il);
  o0.w = f2bf((bf2f(va0.w) + bf2f(vb0.w)) * il);
  o1.x = f2bf((bf2f(va1.x) + bf2f(vb1.x)) * il);
  o1.y = f2bf((bf2f(va1.y) + bf2f(vb1.y)) * il);
  o1.z = f2bf((bf2f(va1.z) + bf2f(vb1.z)) * il);
  o1.w = f2bf((bf2f(va1.w) + bf2f(vb1.w)) * il);
  *(ushort4*)dst = o0;
  *(ushort4*)(dst + 4) = o1;
}

// ---------------- GEMM2 (r1/r6-measured fast variant): 256x128 tile, 8 waves, pipelined ----------------
__device__ __forceinline__ void gemm_pipe(const unsigned short* __restrict__ Ap,
                                          const unsigned short* __restrict__ Bp,
                                          int m0, int n0, f32x4 (&acc)[4][4]) {
  extern __shared__ unsigned short glds[];
  unsigned short* As = glds;          // [2][256*64]
  unsigned short* Bs = glds + 32768;  // [2][128*64]
  const int tid = threadIdx.x;
  const int w = tid >> 6, lane = tid & 63;
  const int fr = lane & 15, g = lane >> 4;
  const int wm = (w >> 1) << 6;      // 0,64,128,192
  const int wn = (w & 1) << 6;       // 0,64
  const int q = tid >> 3, jp = tid & 7;

  auto stageA = [&](int buf, int kk) {
#pragma unroll
    for (int i = 0; i < 4; ++i) {
      const int row = q + (i << 6);
      gl_lds16(Ap + (size_t)(m0 + row) * 2048 + kk + ((jp ^ (row & 7)) << 3),
               As + buf * 16384 + (row << 6) + (jp << 3));
    }
  };
  auto stageB = [&](int buf, int kk) {
#pragma unroll
    for (int i = 0; i < 2; ++i) {
      const int row = q + (i << 6);
      gl_lds16(Bp + (size_t)(n0 + row) * 2048 + kk + ((jp ^ (row & 7)) << 3),
               Bs + buf * 8192 + (row << 6) + (jp << 3));
    }
  };

  stageA(0, 0); stageB(0, 0);
  int cur = 0;
#pragma unroll 2
  for (int t = 0; t < 32; ++t) {
    if (t < 31) {
      const int kn = (t + 1) << 6;
      stageA(cur ^ 1, kn); stageB(cur ^ 1, kn);
      asm volatile("s_waitcnt vmcnt(6)" ::: "memory");
    } else {
      asm volatile("s_waitcnt vmcnt(0)" ::: "memory");
    }
    __builtin_amdgcn_s_barrier();
    FENCE();

    const unsigned short* Ab = As + cur * 16384;
    const unsigned short* Bb = Bs + cur * 8192;

    bf16x8 af[4][2], bv[2][2];
#pragma unroll
    for (int i = 0; i < 4; ++i)
#pragma unroll
      for (int ks = 0; ks < 2; ++ks)
        af[i][ks] = *(const bf16x8*)(Ab + ((wm + (i << 4) + fr) << 6) +
                                     ((((ks << 2) + g) ^ (fr & 7)) << 3));
#pragma unroll
    for (int j = 0; j < 2; ++j)
#pragma unroll
      for (int ks = 0; ks < 2; ++ks)
        bv[j][ks] = *(const bf16x8*)(Bb + ((wn + (j << 4) + fr) << 6) +
                                     ((((ks << 2) + g) ^ (fr & 7)) << 3));
    __builtin_amdgcn_s_setprio(1);
#pragma unroll
    for (int ks = 0; ks < 2; ++ks)
#pragma unroll
      for (int i = 0; i < 4; ++i)
#pragma unroll
        for (int j = 0; j < 2; ++j)
          acc[i][j] = MFMA16(af[i][ks], bv[j][ks], acc[i][j]);
    __builtin_amdgcn_s_setprio(0);
    FENCE();
    __builtin_amdgcn_s_barrier();

    bf16x8 bw[2][2];
#pragma unroll
    for (int j = 0; j < 2; ++j)
#pragma unroll
      for (int ks = 0; ks < 2; ++ks)
        bw[j][ks] = *(const bf16x8*)(Bb + ((wn + ((j + 2) << 4) + fr) << 6) +
                                     ((((ks << 2) + g) ^ (fr & 7)) << 3));
    __builtin_amdgcn_s_setprio(1);
#pragma unroll
    for (int ks = 0; ks < 2; ++ks)
#pragma unroll
      for (int i = 0; i < 4; ++i)
#pragma unroll
        for (int j = 0; j < 2; ++j)
          acc[i][j + 2] = MFMA16(af[i][ks], bw[j][ks], acc[i][j + 2]);
    __builtin_amdgcn_s_setprio(0);
    FENCE();
    __builtin_amdgcn_s_barrier();
    cur ^= 1;
  }
}

// grid 256 (16 m-tiles x 16 n-tiles) -> exactly 1 block/CU, 1 round.
__global__ __launch_bounds__(512, 2) void gemm8_out(const unsigned short* __restrict__ A,
                                                    const unsigned short* __restrict__ Bt,
                                                    float* __restrict__ C) {
  const int bid = blockIdx.x;
  const int wg = (bid & 7) * 32 + (bid >> 3);
  const int mt = wg >> 4, nt = wg & 15;
  const int m0 = mt << 8, n0 = nt << 7;
  f32x4 acc[4][4] = {};
  gemm_pipe(A, Bt, m0, n0, acc);

  const int tid = threadIdx.x, w = tid >> 6, lane = tid & 63;
  const int fr = lane & 15, g = lane >> 4;
  const int wm = (w >> 1) << 6, wn = (w & 1) << 6;
  for (int i = 0; i < 4; ++i) {
    const int row = m0 + wm + (i << 4) + (g << 2);
    for (int j = 0; j < 4; ++j) {
      const int col = n0 + wn + (j << 4) + fr;
      for (int r = 0; r < 4; ++r)
        C[(size_t)(row + r) * EMB + col] = acc[i][j][r];
    }
  }
}

extern "C" void kernel_launch(void* const* d_in, const int* in_sizes, int n_in,
                              void* d_out, int out_size, void* d_ws, size_t ws_size,
                              hipStream_t stream) {
  const float* x    = (const float*)d_in[0];
  const float* wqkv = (const float*)d_in[1];
  const float* wout = (const float*)d_in[2];
  float* out = (float*)d_out;

  unsigned short* ws = (unsigned short*)d_ws;
  const size_t NELEM = (size_t)MROWS * EMB;            // 8388608
  unsigned short* xb    = ws;                          // reused as ctx
  unsigned short* wqkvT = xb + NELEM;                  // [6144][2048]; dead after gemm_qkv
  unsigned short* woutT = wqkvT + (size_t)NQKV * EMB;  // [2048][2048]
  unsigned short* Q     = woutT + (size_t)EMB * EMB;   // [32][2048][128]
  unsigned short* K     = Q + NELEM;
  unsigned short* Vt    = K + NELEM;                   // [32][128][2048]
  unsigned short* ctx   = xb;                          // alias: xb dead after gemm_qkv
  unsigned short* Opart = wqkvT;                       // alias: 512*16384 = 8.39M shorts
  float* Lp = (float*)(Opart + ((size_t)512 << 14));   // in wqkvT spare (12.58M region)

  static bool attr_done = false;
  if (!attr_done) {
    (void)hipFuncSetAttribute((const void*)attn,
                              hipFuncAttributeMaxDynamicSharedMemorySize, 81920);
    (void)hipFuncSetAttribute((const void*)gemm8_out,
                              hipFuncAttributeMaxDynamicSharedMemorySize, 98304);
    attr_done = true;
  }

  prep<<<8192 + 6144 + 2048, 256, 0, stream>>>(x, wqkv, wout, xb, wqkvT, woutT);
  gemm_qkv<<<dim3(NQKV / 128, MROWS / 128), 256, 0, stream>>>(xb, wqkvT, Q, K, Vt);
  attn<<<768, 256, 81920, stream>>>(Q, K, Vt, ctx, Opart, Lp);
  attn_combine<<<2048, 256, 0, stream>>>(Opart, Lp, ctx);
  gemm8_out<<<256, 512, 98304, stream>>>(ctx, woutT, out);
}

// Round 9
// 324.173 us; speedup vs baseline: 1.1325x; 1.0963x over previous
//
#include <hip/hip_runtime.h>
#include <cstdint>

// Problem constants: B=2, S=2048, E=2048, H=16, D=128
#define S_LEN 2048
#define EMB   2048
#define NHEAD 16
#define HDIM  128
#define MROWS 4096   // B*S
#define NQKV  6144   // 3*E

typedef __bf16 bf16x8 __attribute__((ext_vector_type(8)));
typedef __bf16 bf16x4 __attribute__((ext_vector_type(4)));
typedef float  f32x4  __attribute__((ext_vector_type(4)));

#define MFMA16(a, b, c) __builtin_amdgcn_mfma_f32_16x16x32_bf16((a), (b), (c), 0, 0, 0)

__device__ __forceinline__ unsigned short f2bf(float f) {
  unsigned u = __builtin_bit_cast(unsigned, f);
  u += 0x7fffu + ((u >> 16) & 1u);   // RNE
  return (unsigned short)(u >> 16);
}
__device__ __forceinline__ float bf2f(unsigned short u) {
  unsigned v = ((unsigned)u) << 16;
  return __builtin_bit_cast(float, v);
}

// async global->LDS, 16B per lane. LDS dest must be wave-uniform base + lane*16.
__device__ __forceinline__ void gl_lds16(const unsigned short* g, unsigned short* l) {
  __builtin_amdgcn_global_load_lds(
      (const __attribute__((address_space(1))) void*)(uintptr_t)g,
      (__attribute__((address_space(3))) void*)(unsigned int)(uintptr_t)l,
      16, 0, 0);
}

#define FENCE() asm volatile("" ::: "memory")

// ---------------- fused preprocessing: cast x + transpose wqkv + transpose wout ----------------
__global__ __launch_bounds__(256) void prep(const float* __restrict__ x,
                                            const float* __restrict__ wqkv,
                                            const float* __restrict__ wout,
                                            unsigned short* __restrict__ xb,
                                            unsigned short* __restrict__ wqkvT,
                                            unsigned short* __restrict__ woutT) {
  const int bid = blockIdx.x;
  if (bid < 8192) {                      // ---- cast x: fp32 -> bf16, 4 elems/thread ----
    int i = (bid * 256 + threadIdx.x) * 4;
    float4 v = *(const float4*)(x + i);
    ushort4 o;
    o.x = f2bf(v.x); o.y = f2bf(v.y); o.z = f2bf(v.z); o.w = f2bf(v.w);
    *(ushort4*)(xb + i) = o;
    return;
  }
  // ---- transpose+cast: in[R][C] fp32 -> out[C][R] bf16 ----
  const float* in; unsigned short* out; int C, tb;
  if (bid < 8192 + 6144) { in = wqkv; out = wqkvT; C = NQKV; tb = bid - 8192; }
  else                   { in = wout; out = woutT; C = EMB;  tb = bid - 8192 - 6144; }
  const int R = EMB;                     // both inputs have 2048 rows
  const int ctiles = C >> 5;
  const int by = (tb / ctiles) << 6;     // in-row block (64)
  const int bx = (tb % ctiles) << 5;     // in-col block (32)
  __shared__ float tile[64][33];
  const int tx = threadIdx.x & 31, ty = threadIdx.x >> 5;   // ty 0..7
  for (int j = 0; j < 64; j += 8)
    tile[ty + j][tx] = in[(size_t)(by + ty + j) * C + bx + tx];
  __syncthreads();
  int c = threadIdx.x >> 4;              // 0..15, +16 second pass
  const int r4 = (threadIdx.x & 15) << 2;
  for (int p = 0; p < 2; ++p, c += 16) {
    ushort4 o;
    o.x = f2bf(tile[r4 + 0][c]);
    o.y = f2bf(tile[r4 + 1][c]);
    o.z = f2bf(tile[r4 + 2][c]);
    o.w = f2bf(tile[r4 + 3][c]);
    *(ushort4*)(out + (size_t)(bx + c) * R + by + r4) = o;
  }
}

// ---------------- GEMM1: C[M=4096][N=6144] = A[M][2048] @ Bt[N][2048]^T ----------------
// Round-0 verified kernel: BK=64, XOR-swizzled LDS, 128x128 tile, 3 blocks/CU TLP.
__global__ __launch_bounds__(256, 3) void gemm_qkv(const unsigned short* __restrict__ A,
                                                   const unsigned short* __restrict__ Bt,
                                                   unsigned short* __restrict__ Qo,
                                                   unsigned short* __restrict__ Ko,
                                                   unsigned short* __restrict__ Vt) {
  __shared__ __align__(16) unsigned short As[128 * 64];
  __shared__ __align__(16) unsigned short Bs[128 * 64];
  const int tid = threadIdx.x;
  const int n0 = blockIdx.x << 7;
  const int m0 = blockIdx.y << 7;
  const int wave = tid >> 6, lane = tid & 63;
  const int wm = (wave & 1) << 6, wn = (wave >> 1) << 6;
  const int fr = lane & 15, g = lane >> 4;
  const int q = tid >> 3;              // staging row (0..31 per issue)
  const int jp = tid & 7;              // staging granule within row
  f32x4 acc[4][4] = {};
  for (int k0 = 0; k0 < 2048; k0 += 64) {
    for (int i = 0; i < 4; ++i) {
      const int row = q + (i << 5);
      const int jsw = (jp ^ (row & 7)) << 3;
      gl_lds16(A + (size_t)(m0 + row) * 2048 + k0 + jsw, As + (row << 6) + (jp << 3));
      gl_lds16(Bt + (size_t)(n0 + row) * 2048 + k0 + jsw, Bs + (row << 6) + (jp << 3));
    }
    __builtin_amdgcn_s_waitcnt(0);
    __syncthreads();
    for (int ks = 0; ks < 2; ++ks) {
      const int slot = (((ks << 2) + g) ^ (fr & 7)) << 3;
      bf16x8 af[4], bfv[4];
      for (int i = 0; i < 4; ++i) af[i]  = *(const bf16x8*)(As + ((wm + (i << 4) + fr) << 6) + slot);
      for (int j = 0; j < 4; ++j) bfv[j] = *(const bf16x8*)(Bs + ((wn + (j << 4) + fr) << 6) + slot);
      for (int i = 0; i < 4; ++i)
        for (int j = 0; j < 4; ++j)
          acc[i][j] = MFMA16(af[i], bfv[j], acc[i][j]);
    }
    __syncthreads();
  }
  const int which = n0 >> 11;          // 0=Q 1=K 2=V
  const int h = (n0 >> 7) & 15;
  const int bb = m0 >> 11;
  const int bh = bb * NHEAD + h;
  for (int i = 0; i < 4; ++i) {
    const int sl = (m0 & (S_LEN - 1)) + wm + (i << 4) + (g << 2);
    for (int j = 0; j < 4; ++j) {
      const int d = wn + (j << 4) + fr;
      if (which == 2) {
        ushort4 pk;
        pk.x = f2bf(acc[i][j][0]); pk.y = f2bf(acc[i][j][1]);
        pk.z = f2bf(acc[i][j][2]); pk.w = f2bf(acc[i][j][3]);
        *(ushort4*)(Vt + ((size_t)bh * HDIM + d) * S_LEN + sl) = pk;
      } else {
        unsigned short* dst = (which == 0) ? Qo : Ko;
        for (int r = 0; r < 4; ++r)
          dst[((size_t)bh * S_LEN + sl + r) * HDIM + d] = f2bf(acc[i][j][r]);
      }
    }
  }
}

// ---------------- Flash attention, DOUBLE-BUFFERED K/V staging, LONGEST-FIRST order ----------------
// 768 blocks, 2/CU (80KB dynamic LDS). New this round: t-slots dispatched longest-first
// (nkt desc) so the 512 co-resident slots take all >=10-tile blocks and short ones backfill
// -> removes the straggler tail of 16-tile blocks starting in the second round.
// order[] sorted by nkt: 16-tile slots {7,8..15,23}, then 14 {6,22}, 12 {5,21}, 10 {4,20}
// (cumulative 512), then 8,6,4,2.
__global__ __launch_bounds__(256, 2) void attn(const unsigned short* __restrict__ Qg,
                                               const unsigned short* __restrict__ Kg,
                                               const unsigned short* __restrict__ Vtg,
                                               unsigned short* __restrict__ ctx,
                                               unsigned short* __restrict__ Opart,
                                               float* __restrict__ Lp) {
  extern __shared__ __align__(16) unsigned short lds[];
  unsigned short* KV = lds;            // K: [2][8192] @0, V: [2][8192] @16384 (shorts)
  unsigned short* Ps = lds + 32768;    // 16KB C-layout-flat
  unsigned short* Qs = lds;            // alias over K0|K1 (dead after qf read)

  static const int order[24] = {7, 8, 9, 10, 11, 12, 13, 14, 15, 23,
                                6, 22, 5, 21, 4, 20, 3, 19, 2, 18, 1, 17, 0, 16};
  const int blk = blockIdx.x;
  const int bh = blk & 31;
  const int t = order[blk >> 5];
  int qt, kt0, nkt, part;
  if (t < 8)       { qt = t;     kt0 = 0;  nkt = 2 * t + 2;       part = -1; }
  else if (t < 16) { qt = t;     kt0 = 0;  nkt = 16;              part = (bh << 3) + (qt - 8); }
  else             { qt = t - 8; kt0 = 16; nkt = 2 * qt - 14;     part = 256 + (bh << 3) + (qt - 8); }

  const int tid = threadIdx.x, wave = tid >> 6, lane = tid & 63;
  const int fr = lane & 15, g = lane >> 4;

  // stage Q tile [128][128], swizzled
  const unsigned short* qsrc = Qg + ((size_t)bh * S_LEN + (qt << 7)) * HDIM;
  for (int i = 0; i < 8; ++i) {
    int s0 = (i * 256 + tid) << 3;
    int q = s0 >> 7, jp = (s0 >> 3) & 15;
    gl_lds16(qsrc + (q << 7) + ((jp ^ (q & 15)) << 3), Qs + s0);
  }
  __builtin_amdgcn_s_waitcnt(0);
  __syncthreads();

  bf16x8 qf[2][4];
  for (int nbq = 0; nbq < 2; ++nbq)
    for (int kd = 0; kd < 4; ++kd) {
      int q = (wave << 5) + (nbq << 4) + fr;
      qf[nbq][kd] = *(const bf16x8*)(Qs + (q << 7) + ((((kd << 2) + g) ^ fr) << 3));
    }
  __syncthreads();  // Qs dead; region becomes K dbuf

  float lsum[2] = {0.f, 0.f};
  f32x4 oacc[2][8] = {};
  const float scale = 0.08838834764831845f;  // 1/sqrt(128)

  const unsigned short* kbase = Kg + (size_t)bh * S_LEN * HDIM;
  const unsigned short* vbase = Vtg + (size_t)bh * HDIM * S_LEN;

  // stage K[64][128] + V[128][64] for tile kt into buffer cur (8 gl_lds per wave)
  auto stageKV = [&](int cur, int kt) {
    const unsigned short* ks = kbase + ((size_t)kt << 6) * HDIM;
    const unsigned short* vs = vbase + (kt << 6);
    unsigned short* Kd = KV + (cur << 13);
    unsigned short* Vd = KV + 16384 + (cur << 13);
#pragma unroll
    for (int i = 0; i < 4; ++i) {
      int s0 = (i * 256 + tid) << 3;
      int key = s0 >> 7, jk = (s0 >> 3) & 15;
      gl_lds16(ks + (key << 7) + ((jk ^ (key & 15)) << 3), Kd + s0);
      int d = s0 >> 6, jv = (s0 >> 3) & 7;
      gl_lds16(vs + (size_t)d * S_LEN + ((jv ^ (d & 7)) << 3), Vd + s0);
    }
  };

  stageKV(0, kt0);   // prologue: tile 0 in flight (8 outstanding/wave)

  for (int kti = 0; kti < nkt; ++kti) {
    const int cur = kti & 1;
    const int kt = kt0 + kti;
    if (kti + 1 < nkt) {
      stageKV(cur ^ 1, kt + 1);                         // issue early (16 outstanding)
      asm volatile("s_waitcnt vmcnt(8)" ::: "memory");  // force tile kti only
    } else {
      asm volatile("s_waitcnt vmcnt(0)" ::: "memory");
    }
    FENCE(); __builtin_amdgcn_s_barrier(); FENCE();     // buf[cur] ready on all waves

    const unsigned short* Kc = KV + (cur << 13);
    const unsigned short* Vc = KV + 16384 + (cur << 13);

    // S^T = K Q^T
    f32x4 sacc[2][4] = {};
    for (int kd = 0; kd < 4; ++kd)
      for (int kb = 0; kb < 4; ++kb) {
        bf16x8 kf = *(const bf16x8*)(Kc + (((kb << 4) + fr) << 7) + ((((kd << 2) + g) ^ fr) << 3));
        sacc[0][kb] = MFMA16(kf, qf[0][kd], sacc[0][kb]);
        sacc[1][kb] = MFMA16(kf, qf[1][kd], sacc[1][kb]);
      }

    // p = exp(s*scale), mask on diagonal tiles; per-lane l partials
    const bool diag = (kt >= 2 * qt);
    for (int nbq = 0; nbq < 2; ++nbq) {
      const int qg = (qt << 7) + (wave << 5) + (nbq << 4) + fr;
      float sum = 0.f;
      for (int kb = 0; kb < 4; ++kb) {
        float p[4];
        for (int r = 0; r < 4; ++r) {
          float v = sacc[nbq][kb][r] * scale;
          if (diag) {
            int keyg = (kt << 6) + (kb << 4) + (g << 2) + r;
            if (keyg > qg) v = -__builtin_inff();
          }
          p[r] = __expf(v);
          sum += p[r];
        }
        ushort4 pk;
        pk.x = f2bf(p[0]); pk.y = f2bf(p[1]);
        pk.z = f2bf(p[2]); pk.w = f2bf(p[3]);
        *(ushort4*)(Ps + (((wave << 3) + (nbq << 2) + kb) << 8) + (lane << 2)) = pk;
      }
      lsum[nbq] += sum;
    }

    // drain Ps ds_writes ONLY (lgkm), keep prefetch DMA (vmcnt) in flight
    asm volatile("s_waitcnt lgkmcnt(0)" ::: "memory");
    __builtin_amdgcn_sched_barrier(0);

    // O += P V (each wave reads only its own Ps region)
    for (int kc = 0; kc < 2; ++kc) {
      const int kbr = (kc << 1) + (g >> 1);
      bf16x8 ap[2];
      for (int h2 = 0; h2 < 2; ++h2) {
        const unsigned short* pb =
            Ps + (((wave << 3) + (h2 << 2) + kbr) << 8) + ((g & 1) << 7) + (fr << 2);
        bf16x4 a0 = *(const bf16x4*)pb;
        bf16x4 a1 = *(const bf16x4*)(pb + 64);
        bf16x8 a;
        a[0] = a0[0]; a[1] = a0[1]; a[2] = a0[2]; a[3] = a0[3];
        a[4] = a1[0]; a[5] = a1[1]; a[6] = a1[2]; a[7] = a1[3];
        ap[h2] = a;
      }
      for (int nd = 0; nd < 8; ++nd) {
        bf16x8 bv = *(const bf16x8*)(Vc + (((nd << 4) + fr) << 6) + ((((kc << 2) + g) ^ (fr & 7)) << 3));
        oacc[0][nd] = MFMA16(ap[0], bv, oacc[0][nd]);
        oacc[1][nd] = MFMA16(ap[1], bv, oacc[1][nd]);
      }
    }
    FENCE(); __builtin_amdgcn_s_barrier(); FENCE();   // all waves done with buf[cur]
  }

  // reduce l partials across the 4 key-groups (once, not per-iter)
  for (int nbq = 0; nbq < 2; ++nbq) {
    lsum[nbq] += __shfl_xor(lsum[nbq], 16);
    lsum[nbq] += __shfl_xor(lsum[nbq], 32);
  }

  if (part < 0) {
    const int b = bh >> 4, h = bh & 15;
    for (int mq = 0; mq < 2; ++mq)
      for (int r = 0; r < 4; ++r) {
        float lv = __shfl(lsum[mq], (lane & 48) | ((g << 2) + r));
        const float il = 1.0f / lv;
        const int s = (qt << 7) + (wave << 5) + (mq << 4) + (g << 2) + r;
        unsigned short* dst = ctx + ((size_t)(b * S_LEN + s) * EMB) + (h << 7);
        for (int nd = 0; nd < 8; ++nd)
          dst[(nd << 4) + fr] = f2bf(oacc[mq][nd][r] * il);
      }
  } else {
    unsigned short* Ob = Opart + ((size_t)part << 14);
    for (int mq = 0; mq < 2; ++mq)
      for (int r = 0; r < 4; ++r) {
        const int ql = (wave << 5) + (mq << 4) + (g << 2) + r;
        unsigned short* dst = Ob + (ql << 7);
        for (int nd = 0; nd < 8; ++nd)
          dst[(nd << 4) + fr] = f2bf(oacc[mq][nd][r]);
      }
    if (g == 0)
      for (int nbq = 0; nbq < 2; ++nbq) {
        const int ql = (wave << 5) + (nbq << 4) + fr;
        Lp[(part << 7) + ql] = lsum[nbq];
      }
  }
}

// ---------------- combine partials for qt in [8,16) ----------------
__global__ void attn_combine(const unsigned short* __restrict__ Op,
                             const float* __restrict__ Lp,
                             unsigned short* __restrict__ ctx) {
  const int tid = threadIdx.x;
  const int rid = blockIdx.x * 16 + (tid >> 4);  // 0..32767
  const int l16 = tid & 15;
  const int bh = rid >> 10;
  const int qtl = (rid >> 7) & 7;
  const int ql = rid & 127;
  const int p = (bh << 3) + qtl;
  const float lA = Lp[(p << 7) + ql];
  const float lB = Lp[((256 + p) << 7) + ql];
  const float il = 1.0f / (lA + lB);
  const int d0 = l16 << 3;
  const unsigned short* a = Op + ((size_t)p << 14) + (ql << 7) + d0;
  const unsigned short* b = Op + ((size_t)(256 + p) << 14) + (ql << 7) + d0;
  const int bb = bh >> 4, h = bh & 15;
  const int s = ((qtl + 8) << 7) + ql;
  unsigned short* dst = ctx + ((size_t)(bb * S_LEN + s) * EMB) + (h << 7) + d0;
  ushort4 va0 = *(const ushort4*)a, va1 = *(const ushort4*)(a + 4);
  ushort4 vb0 = *(const ushort4*)b, vb1 = *(const ushort4*)(b + 4);
  ushort4 o0, o1;
  o0.x = f2bf((bf2f(va0.x) + bf2f(vb0.x)) * il);
  o0.y = f2bf((bf2f(va0.y) + bf2f(vb0.y)) * il);
  o0.z = f2bf((bf2f(va0.z) + bf2f(vb0.z)) * il);
  o0.w = f2bf((bf2f(va0.w) + bf2f(vb0.w)) * il);
  o1.x = f2bf((bf2f(va1.x) + bf2f(vb1.x)) * il);
  o1.y = f2bf((bf2f(va1.y) + bf2f(vb1.y)) * il);
  o1.z = f2bf((bf2f(va1.z) + bf2f(vb1.z)) * il);
  o1.w = f2bf((bf2f(va1.w) + bf2f(vb1.w)) * il);
  *(ushort4*)dst = o0;
  *(ushort4*)(dst + 4) = o1;
}

// ---------------- GEMM2 (r1/r6-measured fast variant): 256x128 tile, 8 waves, pipelined ----------------
__device__ __forceinline__ void gemm_pipe(const unsigned short* __restrict__ Ap,
                                          const unsigned short* __restrict__ Bp,
                                          int m0, int n0, f32x4 (&acc)[4][4]) {
  extern __shared__ unsigned short glds[];
  unsigned short* As = glds;          // [2][256*64]
  unsigned short* Bs = glds + 32768;  // [2][128*64]
  const int tid = threadIdx.x;
  const int w = tid >> 6, lane = tid & 63;
  const int fr = lane & 15, g = lane >> 4;
  const int wm = (w >> 1) << 6;      // 0,64,128,192
  const int wn = (w & 1) << 6;       // 0,64
  const int q = tid >> 3, jp = tid & 7;

  auto stageA = [&](int buf, int kk) {
#pragma unroll
    for (int i = 0; i < 4; ++i) {
      const int row = q + (i << 6);
      gl_lds16(Ap + (size_t)(m0 + row) * 2048 + kk + ((jp ^ (row & 7)) << 3),
               As + buf * 16384 + (row << 6) + (jp << 3));
    }
  };
  auto stageB = [&](int buf, int kk) {
#pragma unroll
    for (int i = 0; i < 2; ++i) {
      const int row = q + (i << 6);
      gl_lds16(Bp + (size_t)(n0 + row) * 2048 + kk + ((jp ^ (row & 7)) << 3),
               Bs + buf * 8192 + (row << 6) + (jp << 3));
    }
  };

  stageA(0, 0); stageB(0, 0);
  int cur = 0;
#pragma unroll 2
  for (int t = 0; t < 32; ++t) {
    if (t < 31) {
      const int kn = (t + 1) << 6;
      stageA(cur ^ 1, kn); stageB(cur ^ 1, kn);
      asm volatile("s_waitcnt vmcnt(6)" ::: "memory");
    } else {
      asm volatile("s_waitcnt vmcnt(0)" ::: "memory");
    }
    __builtin_amdgcn_s_barrier();
    FENCE();

    const unsigned short* Ab = As + cur * 16384;
    const unsigned short* Bb = Bs + cur * 8192;

    bf16x8 af[4][2], bv[2][2];
#pragma unroll
    for (int i = 0; i < 4; ++i)
#pragma unroll
      for (int ks = 0; ks < 2; ++ks)
        af[i][ks] = *(const bf16x8*)(Ab + ((wm + (i << 4) + fr) << 6) +
                                     ((((ks << 2) + g) ^ (fr & 7)) << 3));
#pragma unroll
    for (int j = 0; j < 2; ++j)
#pragma unroll
      for (int ks = 0; ks < 2; ++ks)
        bv[j][ks] = *(const bf16x8*)(Bb + ((wn + (j << 4) + fr) << 6) +
                                     ((((ks << 2) + g) ^ (fr & 7)) << 3));
    __builtin_amdgcn_s_setprio(1);
#pragma unroll
    for (int ks = 0; ks < 2; ++ks)
#pragma unroll
      for (int i = 0; i < 4; ++i)
#pragma unroll
        for (int j = 0; j < 2; ++j)
          acc[i][j] = MFMA16(af[i][ks], bv[j][ks], acc[i][j]);
    __builtin_amdgcn_s_setprio(0);
    FENCE();
    __builtin_amdgcn_s_barrier();

    bf16x8 bw[2][2];
#pragma unroll
    for (int j = 0; j < 2; ++j)
#pragma unroll
      for (int ks = 0; ks < 2; ++ks)
        bw[j][ks] = *(const bf16x8*)(Bb + ((wn + ((j + 2) << 4) + fr) << 6) +
                                     ((((ks << 2) + g) ^ (fr & 7)) << 3));
    __builtin_amdgcn_s_setprio(1);
#pragma unroll
    for (int ks = 0; ks < 2; ++ks)
#pragma unroll
      for (int i = 0; i < 4; ++i)
#pragma unroll
        for (int j = 0; j < 2; ++j)
          acc[i][j + 2] = MFMA16(af[i][ks], bw[j][ks], acc[i][j + 2]);
    __builtin_amdgcn_s_setprio(0);
    FENCE();
    __builtin_amdgcn_s_barrier();
    cur ^= 1;
  }
}

// grid 256 (16 m-tiles x 16 n-tiles) -> exactly 1 block/CU, 1 round.
__global__ __launch_bounds__(512, 2) void gemm8_out(const unsigned short* __restrict__ A,
                                                    const unsigned short* __restrict__ Bt,
                                                    float* __restrict__ C) {
  const int bid = blockIdx.x;
  const int wg = (bid & 7) * 32 + (bid >> 3);
  const int mt = wg >> 4, nt = wg & 15;
  const int m0 = mt << 8, n0 = nt << 7;
  f32x4 acc[4][4] = {};
  gemm_pipe(A, Bt, m0, n0, acc);

  const int tid = threadIdx.x, w = tid >> 6, lane = tid & 63;
  const int fr = lane & 15, g = lane >> 4;
  const int wm = (w >> 1) << 6, wn = (w & 1) << 6;
  for (int i = 0; i < 4; ++i) {
    const int row = m0 + wm + (i << 4) + (g << 2);
    for (int j = 0; j < 4; ++j) {
      const int col = n0 + wn + (j << 4) + fr;
      for (int r = 0; r < 4; ++r)
        C[(size_t)(row + r) * EMB + col] = acc[i][j][r];
    }
  }
}

extern "C" void kernel_launch(void* const* d_in, const int* in_sizes, int n_in,
                              void* d_out, int out_size, void* d_ws, size_t ws_size,
                              hipStream_t stream) {
  const float* x    = (const float*)d_in[0];
  const float* wqkv = (const float*)d_in[1];
  const float* wout = (const float*)d_in[2];
  float* out = (float*)d_out;

  unsigned short* ws = (unsigned short*)d_ws;
  const size_t NELEM = (size_t)MROWS * EMB;            // 8388608
  unsigned short* xb    = ws;                          // reused as ctx
  unsigned short* wqkvT = xb + NELEM;                  // [6144][2048]; dead after gemm_qkv
  unsigned short* woutT = wqkvT + (size_t)NQKV * EMB;  // [2048][2048]
  unsigned short* Q     = woutT + (size_t)EMB * EMB;   // [32][2048][128]
  unsigned short* K     = Q + NELEM;
  unsigned short* Vt    = K + NELEM;                   // [32][128][2048]
  unsigned short* ctx   = xb;                          // alias: xb dead after gemm_qkv
  unsigned short* Opart = wqkvT;                       // alias: 512*16384 = 8.39M shorts
  float* Lp = (float*)(Opart + ((size_t)512 << 14));   // in wqkvT spare (12.58M region)

  static bool attr_done = false;
  if (!attr_done) {
    (void)hipFuncSetAttribute((const void*)attn,
                              hipFuncAttributeMaxDynamicSharedMemorySize, 81920);
    (void)hipFuncSetAttribute((const void*)gemm8_out,
                              hipFuncAttributeMaxDynamicSharedMemorySize, 98304);
    attr_done = true;
  }

  prep<<<8192 + 6144 + 2048, 256, 0, stream>>>(x, wqkv, wout, xb, wqkvT, woutT);
  gemm_qkv<<<dim3(NQKV / 128, MROWS / 128), 256, 0, stream>>>(xb, wqkvT, Q, K, Vt);
  attn<<<768, 256, 81920, stream>>>(Q, K, Vt, ctx, Opart, Lp);
  attn_combine<<<2048, 256, 0, stream>>>(Opart, Lp, ctx);
  gemm8_out<<<256, 512, 98304, stream>>>(ctx, woutT, out);
}